// Round 1
// baseline (251.195 us; speedup 1.0000x reference)
//
#include <hip/hip_runtime.h>

#define BB 8
#define HH 1024
#define WW 1280
#define EPSF 1e-7f

__global__ __launch_bounds__(256) void synth_view_kernel(
    const float* __restrict__ img, const float* __restrict__ disp,
    const float* __restrict__ srcK, const float* __restrict__ tgtK,
    const float* __restrict__ trans, float* __restrict__ out)
{
    const int x = blockIdx.x * blockDim.x + threadIdx.x;
    const int y = blockIdx.y;
    const int b = blockIdx.z;
    if (x >= WW) return;

    const float* sK = srcK + b * 16;   // wave-uniform -> scalar loads
    const float* tK = tgtK + b * 16;
    const float* tv = trans + b * 3;

    // Analytic inverse of source_K's top-left 3x3 (block-diagonal 4x4 => same as inv(K4)[:3,:3])
    float a00 = sK[0], a01 = sK[1], a02 = sK[2];
    float a10 = sK[4], a11 = sK[5], a12 = sK[6];
    float a20 = sK[8], a21 = sK[9], a22 = sK[10];
    float det = a00*(a11*a22 - a12*a21)
              - a01*(a10*a22 - a12*a20)
              + a02*(a10*a21 - a11*a20);
    float rdet = 1.0f / det;
    float i00 =  (a11*a22 - a12*a21) * rdet;
    float i01 = -(a01*a22 - a02*a21) * rdet;
    float i02 =  (a01*a12 - a02*a11) * rdet;
    float i10 = -(a10*a22 - a12*a20) * rdet;
    float i11 =  (a00*a22 - a02*a20) * rdet;
    float i12 = -(a00*a12 - a02*a10) * rdet;
    float i20 =  (a10*a21 - a11*a20) * rdet;
    float i21 = -(a00*a21 - a01*a20) * rdet;
    float i22 =  (a00*a11 - a01*a10) * rdet;

    // P = (target_K4 @ T)[:3,:], T = I with translation column
    float t0 = tv[0], t1 = tv[1], t2 = tv[2];
    float p00 = tK[0],  p01 = tK[1],  p02 = tK[2];
    float p03 = tK[0]*t0 + tK[1]*t1 + tK[2]*t2 + tK[3];
    float p10 = tK[4],  p11 = tK[5],  p12 = tK[6];
    float p13 = tK[4]*t0 + tK[5]*t1 + tK[6]*t2 + tK[7];
    float p20 = tK[8],  p21 = tK[9],  p22 = tK[10];
    float p23 = tK[8]*t0 + tK[9]*t1 + tK[10]*t2 + tK[11];

    const long long pixidx = (long long)b * (HH * WW) + (long long)y * WW + x;
    float dsp = disp[pixidx];
    const float min_disp = 1.0f / 255.0f;
    const float max_disp = 1.0f / 10.0f;
    float depth = 1.0f / (min_disp + (max_disp - min_disp) * dsp);

    float fx = (float)x, fy = (float)y;
    float camx = (i00*fx + i01*fy + i02) * depth;
    float camy = (i10*fx + i11*fy + i12) * depth;
    float camz = (i20*fx + i21*fy + i22) * depth;

    float cpx = p00*camx + p01*camy + p02*camz + p03;
    float cpy = p10*camx + p11*camy + p12*camz + p13;
    float cpz = p20*camx + p21*camy + p22*camz + p23;

    float rz = 1.0f / (cpz + EPSF);
    float px = cpx * rz;
    float py = cpy * rz;

    // grid = (pc/[W-1,H-1] - 0.5)*2 ; then grid_sample unnormalize (align_corners=False)
    float gx = (px / (float)(WW - 1) - 0.5f) * 2.0f;
    float gy = (py / (float)(HH - 1) - 0.5f) * 2.0f;
    float sx = (gx + 1.0f) * (float)WW * 0.5f - 0.5f;
    float sy = (gy + 1.0f) * (float)HH * 0.5f - 0.5f;

    float x0f = floorf(sx), y0f = floorf(sy);
    float wx = sx - x0f, wy = sy - y0f;
    int x0 = min(max((int)x0f,     0), WW - 1);
    int x1 = min(max((int)x0f + 1, 0), WW - 1);
    int y0 = min(max((int)y0f,     0), HH - 1);
    int y1 = min(max((int)y0f + 1, 0), HH - 1);

    float w00 = (1.0f - wx) * (1.0f - wy);
    float w01 = wx * (1.0f - wy);
    float w10 = (1.0f - wx) * wy;
    float w11 = wx * wy;

    const float* imb = img + (long long)b * 3 * HH * WW;
    long long o00 = (long long)y0 * WW + x0;
    long long o01 = (long long)y0 * WW + x1;
    long long o10 = (long long)y1 * WW + x0;
    long long o11 = (long long)y1 * WW + x1;
    float* outb = out + (long long)b * 3 * HH * WW + (long long)y * WW + x;

#pragma unroll
    for (int c = 0; c < 3; ++c) {
        const float* ic = imb + (long long)c * HH * WW;
        float v = ic[o00]*w00 + ic[o01]*w01 + ic[o10]*w10 + ic[o11]*w11;
        outb[(long long)c * HH * WW] = v;
    }
}

extern "C" void kernel_launch(void* const* d_in, const int* in_sizes, int n_in,
                              void* d_out, int out_size, void* d_ws, size_t ws_size,
                              hipStream_t stream) {
    const float* img   = (const float*)d_in[0];
    const float* disp  = (const float*)d_in[1];
    const float* srcK  = (const float*)d_in[2];
    const float* tgtK  = (const float*)d_in[3];
    const float* trans = (const float*)d_in[4];
    float* out = (float*)d_out;

    dim3 block(256, 1, 1);
    dim3 grid(WW / 256, HH, BB);  // 1280/256=5, y=row, z=batch
    synth_view_kernel<<<grid, block, 0, stream>>>(img, disp, srcK, tgtK, trans, out);
}